// Round 12
// baseline (1910.461 us; speedup 1.0000x reference)
//
#include <hip/hip_runtime.h>

#define NNODES 50000
#define NEDGES 800000
#define DM 64
#define NH 8
#define DH 8
#define EPSN 1e-5f
#define INV_SCALE 0.3535533905932738f   // 1/sqrt(8)

// ---------------------------------------------------------------------------
// Tiled GEMM (proven bit-equivalent to naive sgemm in rounds 3-5):
// C[N x KB] = act(A[N x KA] @ W[woff..] + bias[boff..]) (+ C residual)
// 256 threads; thread computes R rows x 4 cols; A,W staged in LDS.
// STATS: also accumulates per-column sum/sumsq into stats[0..KB-1],[KB..2KB-1].
// ---------------------------------------------------------------------------
template<int KA, int KB, int R, bool RELU, bool RES, bool STATS>
__global__ __launch_bounds__(256) void gemm_k(const float* __restrict__ A,
    const float* __restrict__ W, int woff,
    const float* __restrict__ bias, int boff,
    float* __restrict__ C, float* __restrict__ stats, int Nrows)
{
    constexpr int CG   = KB / 4;        // col groups
    constexpr int RG   = 256 / CG;      // row groups
    constexpr int ROWS = RG * R;        // rows per block
    constexpr int APAD = KA + 4;        // %4==0 -> aligned float4 LDS reads

    __shared__ __align__(16) float sW[KA * KB];
    __shared__ __align__(16) float sA[ROWS * APAD];

    const int tid  = threadIdx.x;
    const int row0 = blockIdx.x * ROWS;

    for (int i = tid; i < KA * KB; i += 256) sW[i] = W[woff + i];
    for (int i = tid; i < ROWS * KA; i += 256) {
        int r = i / KA, k = i - r * KA;
        int gr = row0 + r;
        sA[r * APAD + k] = (gr < Nrows) ? A[(size_t)gr * KA + k] : 0.0f;
    }
    __syncthreads();

    const int cg = tid % CG, rg = tid / CG;
    const int c0 = cg * 4, r0 = rg * R;

    float4 acc[R];
#pragma unroll
    for (int rr = 0; rr < R; rr++) acc[rr] = make_float4(0.f, 0.f, 0.f, 0.f);

#pragma unroll
    for (int k = 0; k < KA; k += 4) {
        float4 w0 = *(const float4*)&sW[(k + 0) * KB + c0];
        float4 w1 = *(const float4*)&sW[(k + 1) * KB + c0];
        float4 w2 = *(const float4*)&sW[(k + 2) * KB + c0];
        float4 w3 = *(const float4*)&sW[(k + 3) * KB + c0];
#pragma unroll
        for (int rr = 0; rr < R; rr++) {
            float4 av = *(const float4*)&sA[(r0 + rr) * APAD + k];
            acc[rr].x += av.x * w0.x + av.y * w1.x + av.z * w2.x + av.w * w3.x;
            acc[rr].y += av.x * w0.y + av.y * w1.y + av.z * w2.y + av.w * w3.y;
            acc[rr].z += av.x * w0.z + av.y * w1.z + av.z * w2.z + av.w * w3.z;
            acc[rr].w += av.x * w0.w + av.y * w1.w + av.z * w2.w + av.w * w3.w;
        }
    }

    float4 bv = make_float4(0.f, 0.f, 0.f, 0.f);
    if (bias) {
        bv.x = bias[boff + c0];     bv.y = bias[boff + c0 + 1];
        bv.z = bias[boff + c0 + 2]; bv.w = bias[boff + c0 + 3];
    }

    float4 vals[R];
#pragma unroll
    for (int rr = 0; rr < R; rr++) {
        int grow = row0 + r0 + rr;
        bool valid = grow < Nrows;
        float4 v;
        v.x = acc[rr].x + bv.x; v.y = acc[rr].y + bv.y;
        v.z = acc[rr].z + bv.z; v.w = acc[rr].w + bv.w;
        if (RELU) {
            v.x = fmaxf(v.x, 0.f); v.y = fmaxf(v.y, 0.f);
            v.z = fmaxf(v.z, 0.f); v.w = fmaxf(v.w, 0.f);
        }
        if (valid) {
            if (RES) {
                float4 old = *(const float4*)&C[(size_t)grow * KB + c0];
                v.x += old.x; v.y += old.y; v.z += old.z; v.w += old.w;
            }
            *(float4*)&C[(size_t)grow * KB + c0] = v;
        } else {
            v = make_float4(0.f, 0.f, 0.f, 0.f);
        }
        vals[rr] = v;
    }

    if (STATS) {
        __syncthreads();
        float4 cs = make_float4(0.f, 0.f, 0.f, 0.f);
#pragma unroll
        for (int rr = 0; rr < R; rr++) {
            cs.x += vals[rr].x; cs.y += vals[rr].y;
            cs.z += vals[rr].z; cs.w += vals[rr].w;
        }
        *(float4*)&sA[rg * KB + c0] = cs;
        __syncthreads();
        if (tid < KB) {
            float s = 0.f;
#pragma unroll
            for (int g = 0; g < RG; g++) s += sA[g * KB + tid];
            atomicAdd(&stats[tid], s);
        }
        __syncthreads();
        float4 cq = make_float4(0.f, 0.f, 0.f, 0.f);
#pragma unroll
        for (int rr = 0; rr < R; rr++) {
            cq.x += vals[rr].x * vals[rr].x; cq.y += vals[rr].y * vals[rr].y;
            cq.z += vals[rr].z * vals[rr].z; cq.w += vals[rr].w * vals[rr].w;
        }
        *(float4*)&sA[rg * KB + c0] = cq;
        __syncthreads();
        if (tid < KB) {
            float s = 0.f;
#pragma unroll
            for (int g = 0; g < RG; g++) s += sA[g * KB + tid];
            atomicAdd(&stats[KB + tid], s);
        }
    }
}

// stats[0..63]=sum, [64..127]=sumsq -> [128..191]=mu, [192..255]=istd
__global__ void bn_fin(float* __restrict__ stats)
{
    int c = threadIdx.x;
    float mu  = stats[c] * (1.0f / NNODES);
    float var = stats[64 + c] * (1.0f / NNODES) - mu * mu;   // biased (jnp.var)
    stats[128 + c] = mu;
    stats[192 + c] = rsqrtf(fmaxf(var, 0.0f) + EPSN);
}

__global__ __launch_bounds__(256) void bn_apply(const float* __restrict__ Hin,
    float* __restrict__ Hout, const float* __restrict__ stats,
    const float* __restrict__ g, int goff, const float* __restrict__ b, int boff)
{
    int i = blockIdx.x * 256 + threadIdx.x;
    if (i >= NNODES * DM) return;
    int c = i & 63;
    float mu = stats[128 + c], istd = stats[192 + c];
    Hout[i] = (Hin[i] - mu) * istd * g[goff + c] + b[boff + c];
}

// ---------------------------------------------------------------------------
// CSR by dst: count -> scan -> fill. All on-device, graph-capture safe.
// ---------------------------------------------------------------------------
__global__ __launch_bounds__(256) void zero_int_k(int* __restrict__ p, int n)
{
    int i = blockIdx.x * 256 + threadIdx.x;
    if (i < n) p[i] = 0;
}

__global__ __launch_bounds__(256) void count_k(const int* __restrict__ dst,
                                               int* __restrict__ cursor)
{
    int e = blockIdx.x * 256 + threadIdx.x;
    if (e < NEDGES) atomicAdd(&cursor[dst[e]], 1);
}

__global__ __launch_bounds__(1024) void scan_k(int* __restrict__ cursor,
                                               int* __restrict__ rowptr)
{
    __shared__ int part[1024];
    const int C = (NNODES + 1023) / 1024;   // 49
    const int t = threadIdx.x;
    const int lo = t * C;
    const int hi = (lo + C < NNODES) ? lo + C : NNODES;
    int s = 0;
    for (int i = lo; i < hi; i++) s += cursor[i];
    part[t] = s;
    __syncthreads();
    if (t == 0) {
        int acc = 0;
        for (int i = 0; i < 1024; i++) { int v = part[i]; part[i] = acc; acc += v; }
    }
    __syncthreads();
    int acc = part[t];
    for (int i = lo; i < hi; i++) {
        int dgi = cursor[i];
        rowptr[i] = acc;
        cursor[i] = acc;
        acc += dgi;
    }
    if (hi == NNODES && lo < NNODES) rowptr[NNODES] = acc;
}

__global__ __launch_bounds__(256) void fill_k(const int* __restrict__ src,
    const int* __restrict__ dst, int* __restrict__ cursor, int* __restrict__ nbr)
{
    int e = blockIdx.x * 256 + threadIdx.x;
    if (e >= NEDGES) return;
    int pos = atomicAdd(&cursor[dst[e]], 1);
    nbr[pos] = src[e];
}

// ---------------------------------------------------------------------------
// Attention — ROUND 12: single-pass ONLINE double-exp softmax (flash-style,
// branchless rescale). Halves K-gathers and shuffles vs the two-pass form.
// e = exp(clip(K.Q/sqrt8,±10)); running m,S,u with rescale exp(m_old-m_new).
// One wave per dst node; lane t = h*8 + j.
// ---------------------------------------------------------------------------
__global__ __launch_bounds__(64) void attn_k(const float* __restrict__ Q,
    const float* __restrict__ K, const float* __restrict__ V,
    const int* __restrict__ rowptr, const int* __restrict__ nbr,
    float* __restrict__ U)
{
    const int d = blockIdx.x;
    const int t = threadIdx.x;           // t = h*8 + j
    const int e0 = rowptr[d], e1 = rowptr[d + 1];
    const float q = Q[d * DM + t];

    float m = 0.0f, S = 0.0f, u = 0.0f;  // e > 0 always; m=0 safe identity
    for (int p = e0; p < e1; p++) {
        int s = nbr[p];
        float kv = K[s * DM + t] * q;
        float v  = V[s * DM + t];
        kv += __shfl_xor(kv, 1, 64);
        kv += __shfl_xor(kv, 2, 64);
        kv += __shfl_xor(kv, 4, 64);     // all 8 lanes of head h hold the dot
        float sc = fminf(fmaxf(kv * INV_SCALE, -10.f), 10.f);
        float e  = expf(sc);
        float mn = fmaxf(m, e);
        float r  = expf(m - mn);         // rescale old accumulators
        float w  = expf(e - mn);         // weight of this edge
        S = S * r + w;
        u = u * r + w * v;
        m = mn;
    }
    U[d * DM + t] = (S > 0.f) ? u / S : 0.f;
}

__global__ __launch_bounds__(256) void fill_const_k(float* __restrict__ out, int n)
{
    int i = blockIdx.x * 256 + threadIdx.x;
    if (i < n) out[i] = 100.0f;
}

// ---------------------------------------------------------------------------
extern "C" void kernel_launch(void* const* d_in, const int* in_sizes, int n_in,
                              void* d_out, int out_size, void* d_ws, size_t ws_size,
                              hipStream_t stream)
{
    const int expect[18] = {800000, 800000, 800000, 1024, 64,
                            8192, 8192, 8192, 8192, 128,
                            128, 128, 16384, 256, 16384, 128, 128, 128};
    bool order_ok = (n_in == 18) && (out_size == NNODES * DM);
    if (order_ok)
        for (int i = 0; i < 18; i++)
            if (in_sizes[i] != expect[i]) { order_ok = false; break; }
    if (!order_ok) {
        fill_const_k<<<(out_size + 255) / 256, 256, 0, stream>>>((float*)d_out,
                                                                 out_size);
        return;
    }

    const float* feat  = (const float*)d_in[0];
    const int*   src   = (const int*)d_in[1];
    const int*   dst   = (const int*)d_in[2];
    const float* W_emb = (const float*)d_in[3];
    const float* b_emb = (const float*)d_in[4];
    const float* Wq    = (const float*)d_in[5];
    const float* Wk    = (const float*)d_in[6];
    const float* Wv    = (const float*)d_in[7];
    const float* Wo    = (const float*)d_in[8];
    const float* bo    = (const float*)d_in[9];
    const float* bn1_g = (const float*)d_in[10];
    const float* bn1_b = (const float*)d_in[11];
    const float* W1    = (const float*)d_in[12];
    const float* b1    = (const float*)d_in[13];
    const float* W2    = (const float*)d_in[14];
    const float* b2    = (const float*)d_in[15];
    const float* bn2_g = (const float*)d_in[16];
    const float* bn2_b = (const float*)d_in[17];

    const size_t ND = (size_t)NNODES * DM;
    float* ws     = (float*)d_ws;
    float* Hb     = ws;
    float* Qb     = Hb + ND;
    float* Kb     = Qb + ND;
    float* Vb     = Kb + ND;
    float* Ub     = Vb + ND;
    float* stats  = Ub + ND;
    int*   rowptr = (int*)(stats + 256);            // N+1
    int*   cursor = rowptr + (NNODES + 1);          // N
    int*   nbr    = cursor + NNODES;                // E
    float* Fb     = Qb;   // FFN hidden [N,128] aliases Qb+Kb (dead after attn)

    const size_t REQUIRED = (5 * ND + 256 + (NNODES + 1) + NNODES + NEDGES) * 4;
    if (ws_size < REQUIRED) return;

    const int g64 = (NNODES + 63) / 64;   // 782
    const int g32 = (NNODES + 31) / 32;   // 1563
    const int gND = (int)(ND / 256);      // 12500
    const int gE  = (NEDGES + 255) / 256; // 3125

    // CSR by dst
    zero_int_k<<<(NNODES + 255) / 256, 256, 0, stream>>>(cursor, NNODES);
    count_k<<<gE, 256, 0, stream>>>(dst, cursor);
    scan_k<<<1, 1024, 0, stream>>>(cursor, rowptr);
    fill_k<<<gE, 256, 0, stream>>>(src, dst, cursor, nbr);

    // embedding: H = feat @ W_emb + b_emb
    gemm_k<16, 64, 4, false, false, false>
        <<<g64, 256, 0, stream>>>(feat, W_emb, 0, b_emb, 0, Hb, nullptr, NNODES);

    for (int l = 0; l < 2; l++) {
        const int woff  = l * DM * DM;        // 4096
        const int w1off = l * DM * 2 * DM;    // 8192
        const int boff  = l * DM;             // 64
        const int b1off = l * 2 * DM;         // 128

        gemm_k<64, 64, 4, false, false, false>
            <<<g64, 256, 0, stream>>>(Hb, Wq, woff, nullptr, 0, Qb, nullptr, NNODES);
        gemm_k<64, 64, 4, false, false, false>
            <<<g64, 256, 0, stream>>>(Hb, Wk, woff, nullptr, 0, Kb, nullptr, NNODES);
        gemm_k<64, 64, 4, false, false, false>
            <<<g64, 256, 0, stream>>>(Hb, Wv, woff, nullptr, 0, Vb, nullptr, NNODES);

        attn_k<<<NNODES, 64, 0, stream>>>(Qb, Kb, Vb, rowptr, nbr, Ub);

        // h = h_in1 + U @ Wo + bo ; fused BN stats ; BN apply
        hipMemsetAsync(stats, 0, 128 * 4, stream);
        gemm_k<64, 64, 4, false, true, true>
            <<<g64, 256, 0, stream>>>(Ub, Wo, woff, bo, boff, Hb, stats, NNODES);
        bn_fin<<<1, 64, 0, stream>>>(stats);
        bn_apply<<<gND, 256, 0, stream>>>(Hb, Hb, stats, bn1_g, boff, bn1_b, boff);

        // FFN: F = relu(H @ W1 + b1) ; H = H + F @ W2 + b2 ; BN
        gemm_k<64, 128, 4, true, false, false>
            <<<g32, 256, 0, stream>>>(Hb, W1, w1off, b1, b1off, Fb, nullptr, NNODES);
        hipMemsetAsync(stats, 0, 128 * 4, stream);
        gemm_k<128, 64, 2, false, true, true>
            <<<g32, 256, 0, stream>>>(Fb, W2, w1off, b2, boff, Hb, stats, NNODES);
        bn_fin<<<1, 64, 0, stream>>>(stats);
        // last BN of last layer writes the final output directly
        float* outp = (l == 1) ? (float*)d_out : Hb;
        bn_apply<<<gND, 256, 0, stream>>>(Hb, outp, stats, bn2_g, boff, bn2_b, boff);
    }
}

// Round 13
// 830.816 us; speedup vs baseline: 2.2995x; 2.2995x over previous
//
#include <hip/hip_runtime.h>

#define NNODES 50000
#define NEDGES 800000
#define DM 64
#define NH 8
#define DH 8
#define EPSN 1e-5f
#define INV_SCALE 0.3535533905932738f   // 1/sqrt(8)

// ---------------------------------------------------------------------------
// Tiled GEMM:  C[N x KB] = act(A @ W[woff..] + bias[boff..]) (+ C residual)
// 256 threads; thread computes R rows x 4 cols; A,W staged in LDS.
// ROUND 13: #pragma unroll 2 on k-loop + __launch_bounds__(256,2) — r12's
// full unroll spilled (VGPR=256, 1.2 GB scratch traffic per dispatch).
// STATS: also accumulates per-column sum/sumsq into stats[0..KB-1],[KB..2KB-1].
// ---------------------------------------------------------------------------
template<int KA, int KB, int R, bool RELU, bool RES, bool STATS>
__global__ __launch_bounds__(256, 2) void gemm_k(const float* __restrict__ A,
    const float* __restrict__ W, int woff,
    const float* __restrict__ bias, int boff,
    float* __restrict__ C, float* __restrict__ stats, int Nrows)
{
    constexpr int CG   = KB / 4;        // col groups
    constexpr int RG   = 256 / CG;      // row groups
    constexpr int ROWS = RG * R;        // rows per block
    constexpr int APAD = KA + 4;        // %4==0 -> aligned float4 LDS reads

    __shared__ __align__(16) float sW[KA * KB];
    __shared__ __align__(16) float sA[ROWS * APAD];

    const int tid  = threadIdx.x;
    const int row0 = blockIdx.x * ROWS;

    for (int i = tid; i < KA * KB; i += 256) sW[i] = W[woff + i];
    for (int i = tid; i < ROWS * KA; i += 256) {
        int r = i / KA, k = i - r * KA;
        int gr = row0 + r;
        sA[r * APAD + k] = (gr < Nrows) ? A[(size_t)gr * KA + k] : 0.0f;
    }
    __syncthreads();

    const int cg = tid % CG, rg = tid / CG;
    const int c0 = cg * 4, r0 = rg * R;

    float4 acc[R];
#pragma unroll
    for (int rr = 0; rr < R; rr++) acc[rr] = make_float4(0.f, 0.f, 0.f, 0.f);

#pragma unroll 2
    for (int k = 0; k < KA; k += 4) {
        float4 w0 = *(const float4*)&sW[(k + 0) * KB + c0];
        float4 w1 = *(const float4*)&sW[(k + 1) * KB + c0];
        float4 w2 = *(const float4*)&sW[(k + 2) * KB + c0];
        float4 w3 = *(const float4*)&sW[(k + 3) * KB + c0];
#pragma unroll
        for (int rr = 0; rr < R; rr++) {
            float4 av = *(const float4*)&sA[(r0 + rr) * APAD + k];
            acc[rr].x += av.x * w0.x + av.y * w1.x + av.z * w2.x + av.w * w3.x;
            acc[rr].y += av.x * w0.y + av.y * w1.y + av.z * w2.y + av.w * w3.y;
            acc[rr].z += av.x * w0.z + av.y * w1.z + av.z * w2.z + av.w * w3.z;
            acc[rr].w += av.x * w0.w + av.y * w1.w + av.z * w2.w + av.w * w3.w;
        }
    }

    float4 bv = make_float4(0.f, 0.f, 0.f, 0.f);
    if (bias) {
        bv.x = bias[boff + c0];     bv.y = bias[boff + c0 + 1];
        bv.z = bias[boff + c0 + 2]; bv.w = bias[boff + c0 + 3];
    }

    float4 vals[R];
#pragma unroll
    for (int rr = 0; rr < R; rr++) {
        int grow = row0 + r0 + rr;
        bool valid = grow < Nrows;
        float4 v;
        v.x = acc[rr].x + bv.x; v.y = acc[rr].y + bv.y;
        v.z = acc[rr].z + bv.z; v.w = acc[rr].w + bv.w;
        if (RELU) {
            v.x = fmaxf(v.x, 0.f); v.y = fmaxf(v.y, 0.f);
            v.z = fmaxf(v.z, 0.f); v.w = fmaxf(v.w, 0.f);
        }
        if (valid) {
            if (RES) {
                float4 old = *(const float4*)&C[(size_t)grow * KB + c0];
                v.x += old.x; v.y += old.y; v.z += old.z; v.w += old.w;
            }
            *(float4*)&C[(size_t)grow * KB + c0] = v;
        } else {
            v = make_float4(0.f, 0.f, 0.f, 0.f);
        }
        vals[rr] = v;
    }

    if (STATS) {
        __syncthreads();
        float4 cs = make_float4(0.f, 0.f, 0.f, 0.f);
#pragma unroll
        for (int rr = 0; rr < R; rr++) {
            cs.x += vals[rr].x; cs.y += vals[rr].y;
            cs.z += vals[rr].z; cs.w += vals[rr].w;
        }
        *(float4*)&sA[rg * KB + c0] = cs;
        __syncthreads();
        if (tid < KB) {
            float s = 0.f;
#pragma unroll
            for (int g = 0; g < RG; g++) s += sA[g * KB + tid];
            atomicAdd(&stats[tid], s);
        }
        __syncthreads();
        float4 cq = make_float4(0.f, 0.f, 0.f, 0.f);
#pragma unroll
        for (int rr = 0; rr < R; rr++) {
            cq.x += vals[rr].x * vals[rr].x; cq.y += vals[rr].y * vals[rr].y;
            cq.z += vals[rr].z * vals[rr].z; cq.w += vals[rr].w * vals[rr].w;
        }
        *(float4*)&sA[rg * KB + c0] = cq;
        __syncthreads();
        if (tid < KB) {
            float s = 0.f;
#pragma unroll
            for (int g = 0; g < RG; g++) s += sA[g * KB + tid];
            atomicAdd(&stats[KB + tid], s);
        }
    }
}

// stats[0..63]=sum, [64..127]=sumsq -> [128..191]=mu, [192..255]=istd
__global__ void bn_fin(float* __restrict__ stats)
{
    int c = threadIdx.x;
    float mu  = stats[c] * (1.0f / NNODES);
    float var = stats[64 + c] * (1.0f / NNODES) - mu * mu;   // biased (jnp.var)
    stats[128 + c] = mu;
    stats[192 + c] = rsqrtf(fmaxf(var, 0.0f) + EPSN);
}

__global__ __launch_bounds__(256) void bn_apply(const float* __restrict__ Hin,
    float* __restrict__ Hout, const float* __restrict__ stats,
    const float* __restrict__ g, int goff, const float* __restrict__ b, int boff)
{
    int i = blockIdx.x * 256 + threadIdx.x;
    if (i >= NNODES * DM) return;
    int c = i & 63;
    float mu = stats[128 + c], istd = stats[192 + c];
    Hout[i] = (Hin[i] - mu) * istd * g[goff + c] + b[boff + c];
}

// ---------------------------------------------------------------------------
// CSR by dst: count -> scan -> fill. All on-device, graph-capture safe.
// ---------------------------------------------------------------------------
__global__ __launch_bounds__(256) void zero_int_k(int* __restrict__ p, int n)
{
    int i = blockIdx.x * 256 + threadIdx.x;
    if (i < n) p[i] = 0;
}

__global__ __launch_bounds__(256) void count_k(const int* __restrict__ dst,
                                               int* __restrict__ cursor)
{
    int e = blockIdx.x * 256 + threadIdx.x;
    if (e < NEDGES) atomicAdd(&cursor[dst[e]], 1);
}

__global__ __launch_bounds__(1024) void scan_k(int* __restrict__ cursor,
                                               int* __restrict__ rowptr)
{
    __shared__ int part[1024];
    const int C = (NNODES + 1023) / 1024;   // 49
    const int t = threadIdx.x;
    const int lo = t * C;
    const int hi = (lo + C < NNODES) ? lo + C : NNODES;
    int s = 0;
    for (int i = lo; i < hi; i++) s += cursor[i];
    part[t] = s;
    __syncthreads();
    if (t == 0) {
        int acc = 0;
        for (int i = 0; i < 1024; i++) { int v = part[i]; part[i] = acc; acc += v; }
    }
    __syncthreads();
    int acc = part[t];
    for (int i = lo; i < hi; i++) {
        int dgi = cursor[i];
        rowptr[i] = acc;
        cursor[i] = acc;
        acc += dgi;
    }
    if (hi == NNODES && lo < NNODES) rowptr[NNODES] = acc;
}

__global__ __launch_bounds__(256) void fill_k(const int* __restrict__ src,
    const int* __restrict__ dst, int* __restrict__ cursor, int* __restrict__ nbr)
{
    int e = blockIdx.x * 256 + threadIdx.x;
    if (e >= NEDGES) return;
    int pos = atomicAdd(&cursor[dst[e]], 1);
    nbr[pos] = src[e];
}

// ---------------------------------------------------------------------------
// Attention — single-pass online double-exp softmax (r12, verified).
// One wave per dst node; lane t = h*8 + j.
// ---------------------------------------------------------------------------
__global__ __launch_bounds__(64) void attn_k(const float* __restrict__ Q,
    const float* __restrict__ K, const float* __restrict__ V,
    const int* __restrict__ rowptr, const int* __restrict__ nbr,
    float* __restrict__ U)
{
    const int d = blockIdx.x;
    const int t = threadIdx.x;           // t = h*8 + j
    const int e0 = rowptr[d], e1 = rowptr[d + 1];
    const float q = Q[d * DM + t];

    float m = 0.0f, S = 0.0f, u = 0.0f;  // e > 0 always; m=0 safe identity
    for (int p = e0; p < e1; p++) {
        int s = nbr[p];
        float kv = K[s * DM + t] * q;
        float v  = V[s * DM + t];
        kv += __shfl_xor(kv, 1, 64);
        kv += __shfl_xor(kv, 2, 64);
        kv += __shfl_xor(kv, 4, 64);     // all 8 lanes of head h hold the dot
        float sc = fminf(fmaxf(kv * INV_SCALE, -10.f), 10.f);
        float e  = expf(sc);
        float mn = fmaxf(m, e);
        float r  = expf(m - mn);
        float w  = expf(e - mn);
        S = S * r + w;
        u = u * r + w * v;
        m = mn;
    }
    U[d * DM + t] = (S > 0.f) ? u / S : 0.f;
}

__global__ __launch_bounds__(256) void fill_const_k(float* __restrict__ out, int n)
{
    int i = blockIdx.x * 256 + threadIdx.x;
    if (i < n) out[i] = 100.0f;
}

// ---------------------------------------------------------------------------
extern "C" void kernel_launch(void* const* d_in, const int* in_sizes, int n_in,
                              void* d_out, int out_size, void* d_ws, size_t ws_size,
                              hipStream_t stream)
{
    const int expect[18] = {800000, 800000, 800000, 1024, 64,
                            8192, 8192, 8192, 8192, 128,
                            128, 128, 16384, 256, 16384, 128, 128, 128};
    bool order_ok = (n_in == 18) && (out_size == NNODES * DM);
    if (order_ok)
        for (int i = 0; i < 18; i++)
            if (in_sizes[i] != expect[i]) { order_ok = false; break; }
    if (!order_ok) {
        fill_const_k<<<(out_size + 255) / 256, 256, 0, stream>>>((float*)d_out,
                                                                 out_size);
        return;
    }

    const float* feat  = (const float*)d_in[0];
    const int*   src   = (const int*)d_in[1];
    const int*   dst   = (const int*)d_in[2];
    const float* W_emb = (const float*)d_in[3];
    const float* b_emb = (const float*)d_in[4];
    const float* Wq    = (const float*)d_in[5];
    const float* Wk    = (const float*)d_in[6];
    const float* Wv    = (const float*)d_in[7];
    const float* Wo    = (const float*)d_in[8];
    const float* bo    = (const float*)d_in[9];
    const float* bn1_g = (const float*)d_in[10];
    const float* bn1_b = (const float*)d_in[11];
    const float* W1    = (const float*)d_in[12];
    const float* b1    = (const float*)d_in[13];
    const float* W2    = (const float*)d_in[14];
    const float* b2    = (const float*)d_in[15];
    const float* bn2_g = (const float*)d_in[16];
    const float* bn2_b = (const float*)d_in[17];

    const size_t ND = (size_t)NNODES * DM;
    float* ws     = (float*)d_ws;
    float* Hb     = ws;
    float* Qb     = Hb + ND;
    float* Kb     = Qb + ND;
    float* Vb     = Kb + ND;
    float* Ub     = Vb + ND;
    float* stats  = Ub + ND;
    int*   rowptr = (int*)(stats + 256);            // N+1
    int*   cursor = rowptr + (NNODES + 1);          // N
    int*   nbr    = cursor + NNODES;                // E
    float* Fb     = Qb;   // FFN hidden [N,128] aliases Qb+Kb (dead after attn)

    const size_t REQUIRED = (5 * ND + 256 + (NNODES + 1) + NNODES + NEDGES) * 4;
    if (ws_size < REQUIRED) return;

    const int g64 = (NNODES + 63) / 64;   // 782
    const int g32 = (NNODES + 31) / 32;   // 1563
    const int gND = (int)(ND / 256);      // 12500
    const int gE  = (NEDGES + 255) / 256; // 3125

    // CSR by dst
    zero_int_k<<<(NNODES + 255) / 256, 256, 0, stream>>>(cursor, NNODES);
    count_k<<<gE, 256, 0, stream>>>(dst, cursor);
    scan_k<<<1, 1024, 0, stream>>>(cursor, rowptr);
    fill_k<<<gE, 256, 0, stream>>>(src, dst, cursor, nbr);

    // embedding: H = feat @ W_emb + b_emb
    gemm_k<16, 64, 4, false, false, false>
        <<<g64, 256, 0, stream>>>(feat, W_emb, 0, b_emb, 0, Hb, nullptr, NNODES);

    for (int l = 0; l < 2; l++) {
        const int woff  = l * DM * DM;        // 4096
        const int w1off = l * DM * 2 * DM;    // 8192
        const int boff  = l * DM;             // 64
        const int b1off = l * 2 * DM;         // 128

        gemm_k<64, 64, 4, false, false, false>
            <<<g64, 256, 0, stream>>>(Hb, Wq, woff, nullptr, 0, Qb, nullptr, NNODES);
        gemm_k<64, 64, 4, false, false, false>
            <<<g64, 256, 0, stream>>>(Hb, Wk, woff, nullptr, 0, Kb, nullptr, NNODES);
        gemm_k<64, 64, 4, false, false, false>
            <<<g64, 256, 0, stream>>>(Hb, Wv, woff, nullptr, 0, Vb, nullptr, NNODES);

        attn_k<<<NNODES, 64, 0, stream>>>(Qb, Kb, Vb, rowptr, nbr, Ub);

        // h = h_in1 + U @ Wo + bo ; fused BN stats ; BN apply
        hipMemsetAsync(stats, 0, 128 * 4, stream);
        gemm_k<64, 64, 4, false, true, true>
            <<<g64, 256, 0, stream>>>(Ub, Wo, woff, bo, boff, Hb, stats, NNODES);
        bn_fin<<<1, 64, 0, stream>>>(stats);
        bn_apply<<<gND, 256, 0, stream>>>(Hb, Hb, stats, bn1_g, boff, bn1_b, boff);

        // FFN: F = relu(H @ W1 + b1) ; H = H + F @ W2 + b2 ; BN
        gemm_k<64, 128, 4, true, false, false>
            <<<g32, 256, 0, stream>>>(Hb, W1, w1off, b1, b1off, Fb, nullptr, NNODES);
        hipMemsetAsync(stats, 0, 128 * 4, stream);
        gemm_k<128, 64, 2, false, true, true>
            <<<g32, 256, 0, stream>>>(Fb, W2, w1off, b2, boff, Hb, stats, NNODES);
        bn_fin<<<1, 64, 0, stream>>>(stats);
        // last BN of last layer writes the final output directly
        float* outp = (l == 1) ? (float*)d_out : Hb;
        bn_apply<<<gND, 256, 0, stream>>>(Hb, outp, stats, bn2_g, boff, bn2_b, boff);
    }
}

// Round 14
// 729.392 us; speedup vs baseline: 2.6193x; 1.1391x over previous
//
#include <hip/hip_runtime.h>

#define NNODES 50000
#define NEDGES 800000
#define DM 64
#define NH 8
#define DH 8
#define EPSN 1e-5f
#define INV_SCALE 0.3535533905932738f   // 1/sqrt(8)
#define SCAN_BLOCKS 200                  // NNODES = 200 * 250 exactly
#define SCAN_CHUNK  250

// ---------------------------------------------------------------------------
// Tiled GEMM (r13-proven: unroll-2 + launch_bounds(256,2) keeps VGPR <=128,
// no spill):  C[N x KB] = act(A @ W[woff..] + bias[boff..]) (+ C residual)
// STATS: also accumulates per-column sum/sumsq into stats[0..KB-1],[KB..2KB-1].
// ---------------------------------------------------------------------------
template<int KA, int KB, int R, bool RELU, bool RES, bool STATS>
__global__ __launch_bounds__(256, 2) void gemm_k(const float* __restrict__ A,
    const float* __restrict__ W, int woff,
    const float* __restrict__ bias, int boff,
    float* __restrict__ C, float* __restrict__ stats, int Nrows)
{
    constexpr int CG   = KB / 4;
    constexpr int RG   = 256 / CG;
    constexpr int ROWS = RG * R;
    constexpr int APAD = KA + 4;

    __shared__ __align__(16) float sW[KA * KB];
    __shared__ __align__(16) float sA[ROWS * APAD];

    const int tid  = threadIdx.x;
    const int row0 = blockIdx.x * ROWS;

    for (int i = tid; i < KA * KB; i += 256) sW[i] = W[woff + i];
    for (int i = tid; i < ROWS * KA; i += 256) {
        int r = i / KA, k = i - r * KA;
        int gr = row0 + r;
        sA[r * APAD + k] = (gr < Nrows) ? A[(size_t)gr * KA + k] : 0.0f;
    }
    __syncthreads();

    const int cg = tid % CG, rg = tid / CG;
    const int c0 = cg * 4, r0 = rg * R;

    float4 acc[R];
#pragma unroll
    for (int rr = 0; rr < R; rr++) acc[rr] = make_float4(0.f, 0.f, 0.f, 0.f);

#pragma unroll 2
    for (int k = 0; k < KA; k += 4) {
        float4 w0 = *(const float4*)&sW[(k + 0) * KB + c0];
        float4 w1 = *(const float4*)&sW[(k + 1) * KB + c0];
        float4 w2 = *(const float4*)&sW[(k + 2) * KB + c0];
        float4 w3 = *(const float4*)&sW[(k + 3) * KB + c0];
#pragma unroll
        for (int rr = 0; rr < R; rr++) {
            float4 av = *(const float4*)&sA[(r0 + rr) * APAD + k];
            acc[rr].x += av.x * w0.x + av.y * w1.x + av.z * w2.x + av.w * w3.x;
            acc[rr].y += av.x * w0.y + av.y * w1.y + av.z * w2.y + av.w * w3.y;
            acc[rr].z += av.x * w0.z + av.y * w1.z + av.z * w2.z + av.w * w3.z;
            acc[rr].w += av.x * w0.w + av.y * w1.w + av.z * w2.w + av.w * w3.w;
        }
    }

    float4 bv = make_float4(0.f, 0.f, 0.f, 0.f);
    if (bias) {
        bv.x = bias[boff + c0];     bv.y = bias[boff + c0 + 1];
        bv.z = bias[boff + c0 + 2]; bv.w = bias[boff + c0 + 3];
    }

    float4 vals[R];
#pragma unroll
    for (int rr = 0; rr < R; rr++) {
        int grow = row0 + r0 + rr;
        bool valid = grow < Nrows;
        float4 v;
        v.x = acc[rr].x + bv.x; v.y = acc[rr].y + bv.y;
        v.z = acc[rr].z + bv.z; v.w = acc[rr].w + bv.w;
        if (RELU) {
            v.x = fmaxf(v.x, 0.f); v.y = fmaxf(v.y, 0.f);
            v.z = fmaxf(v.z, 0.f); v.w = fmaxf(v.w, 0.f);
        }
        if (valid) {
            if (RES) {
                float4 old = *(const float4*)&C[(size_t)grow * KB + c0];
                v.x += old.x; v.y += old.y; v.z += old.z; v.w += old.w;
            }
            *(float4*)&C[(size_t)grow * KB + c0] = v;
        } else {
            v = make_float4(0.f, 0.f, 0.f, 0.f);
        }
        vals[rr] = v;
    }

    if (STATS) {
        __syncthreads();
        float4 cs = make_float4(0.f, 0.f, 0.f, 0.f);
#pragma unroll
        for (int rr = 0; rr < R; rr++) {
            cs.x += vals[rr].x; cs.y += vals[rr].y;
            cs.z += vals[rr].z; cs.w += vals[rr].w;
        }
        *(float4*)&sA[rg * KB + c0] = cs;
        __syncthreads();
        if (tid < KB) {
            float s = 0.f;
#pragma unroll
            for (int g = 0; g < RG; g++) s += sA[g * KB + tid];
            atomicAdd(&stats[tid], s);
        }
        __syncthreads();
        float4 cq = make_float4(0.f, 0.f, 0.f, 0.f);
#pragma unroll
        for (int rr = 0; rr < R; rr++) {
            cq.x += vals[rr].x * vals[rr].x; cq.y += vals[rr].y * vals[rr].y;
            cq.z += vals[rr].z * vals[rr].z; cq.w += vals[rr].w * vals[rr].w;
        }
        *(float4*)&sA[rg * KB + c0] = cq;
        __syncthreads();
        if (tid < KB) {
            float s = 0.f;
#pragma unroll
            for (int g = 0; g < RG; g++) s += sA[g * KB + tid];
            atomicAdd(&stats[KB + tid], s);
        }
    }
}

// stats[0..63]=sum, [64..127]=sumsq -> [128..191]=mu, [192..255]=istd
__global__ void bn_fin(float* __restrict__ stats)
{
    int c = threadIdx.x;
    float mu  = stats[c] * (1.0f / NNODES);
    float var = stats[64 + c] * (1.0f / NNODES) - mu * mu;   // biased (jnp.var)
    stats[128 + c] = mu;
    stats[192 + c] = rsqrtf(fmaxf(var, 0.0f) + EPSN);
}

__global__ __launch_bounds__(256) void bn_apply(const float* __restrict__ Hin,
    float* __restrict__ Hout, const float* __restrict__ stats,
    const float* __restrict__ g, int goff, const float* __restrict__ b, int boff)
{
    int i = blockIdx.x * 256 + threadIdx.x;
    if (i >= NNODES * DM) return;
    int c = i & 63;
    float mu = stats[128 + c], istd = stats[192 + c];
    Hout[i] = (Hin[i] - mu) * istd * g[goff + c] + b[boff + c];
}

// ---------------------------------------------------------------------------
// CSR by dst — ROUND 14: hierarchical 3-phase scan replaces the single-block
// scan_k (117 us: 1 block, VALUBusy 0.01%, latency-serialized on one CU).
// ---------------------------------------------------------------------------
__global__ __launch_bounds__(256) void zero_int_k(int* __restrict__ p, int n)
{
    int i = blockIdx.x * 256 + threadIdx.x;
    if (i < n) p[i] = 0;
}

__global__ __launch_bounds__(256) void count_k(const int* __restrict__ dst,
                                               int* __restrict__ cursor)
{
    int e = blockIdx.x * 256 + threadIdx.x;
    if (e < NEDGES) atomicAdd(&cursor[dst[e]], 1);
}

// Phase A: block b sums its 250 in-degrees -> bsum[b]
__global__ __launch_bounds__(256) void csr_scanA(const int* __restrict__ cursor,
                                                 int* __restrict__ bsum)
{
    __shared__ int red[256];
    const int base = blockIdx.x * SCAN_CHUNK;
    int s = 0;
    for (int i = threadIdx.x; i < SCAN_CHUNK; i += 256) s += cursor[base + i];
    red[threadIdx.x] = s;
    __syncthreads();
    for (int o = 128; o > 0; o >>= 1) {
        if (threadIdx.x < o) red[threadIdx.x] += red[threadIdx.x + o];
        __syncthreads();
    }
    if (threadIdx.x == 0) bsum[blockIdx.x] = red[0];
}

// Phase B: exclusive scan of the 200 block sums (Hillis-Steele in LDS)
__global__ __launch_bounds__(256) void csr_scanB(int* __restrict__ bsum)
{
    __shared__ int t[256];
    const int tid = threadIdx.x;
    int v = (tid < SCAN_BLOCKS) ? bsum[tid] : 0;
    t[tid] = v;
    __syncthreads();
    for (int off = 1; off < 256; off <<= 1) {
        int x = (tid >= off) ? t[tid - off] : 0;
        __syncthreads();
        t[tid] += x;
        __syncthreads();
    }
    if (tid < SCAN_BLOCKS) bsum[tid] = t[tid] - v;   // exclusive
}

// Phase C: per-block inclusive scan of 250 degrees -> global exclusive offsets
__global__ __launch_bounds__(256) void csr_scanC(int* __restrict__ cursor,
    int* __restrict__ rowptr, const int* __restrict__ bsum)
{
    __shared__ int t[256];
    const int base = blockIdx.x * SCAN_CHUNK;
    const int tid  = threadIdx.x;
    int deg = (tid < SCAN_CHUNK) ? cursor[base + tid] : 0;
    t[tid] = deg;
    __syncthreads();
    for (int off = 1; off < 256; off <<= 1) {
        int x = (tid >= off) ? t[tid - off] : 0;
        __syncthreads();
        t[tid] += x;
        __syncthreads();
    }
    int excl = bsum[blockIdx.x] + t[tid] - deg;
    if (tid < SCAN_CHUNK) {
        rowptr[base + tid] = excl;
        cursor[base + tid] = excl;   // fill-cursor starts at row base
    }
    if (blockIdx.x == 0 && tid == 0) rowptr[NNODES] = NEDGES;  // total in-degree
}

__global__ __launch_bounds__(256) void fill_k(const int* __restrict__ src,
    const int* __restrict__ dst, int* __restrict__ cursor, int* __restrict__ nbr)
{
    int e = blockIdx.x * 256 + threadIdx.x;
    if (e >= NEDGES) return;
    int pos = atomicAdd(&cursor[dst[e]], 1);
    nbr[pos] = src[e];
}

// ---------------------------------------------------------------------------
// Attention — single-pass online double-exp softmax (r12, verified).
// One wave per dst node; lane t = h*8 + j.
// ---------------------------------------------------------------------------
__global__ __launch_bounds__(64) void attn_k(const float* __restrict__ Q,
    const float* __restrict__ K, const float* __restrict__ V,
    const int* __restrict__ rowptr, const int* __restrict__ nbr,
    float* __restrict__ U)
{
    const int d = blockIdx.x;
    const int t = threadIdx.x;           // t = h*8 + j
    const int e0 = rowptr[d], e1 = rowptr[d + 1];
    const float q = Q[d * DM + t];

    float m = 0.0f, S = 0.0f, u = 0.0f;  // e > 0 always; m=0 safe identity
    for (int p = e0; p < e1; p++) {
        int s = nbr[p];
        float kv = K[s * DM + t] * q;
        float v  = V[s * DM + t];
        kv += __shfl_xor(kv, 1, 64);
        kv += __shfl_xor(kv, 2, 64);
        kv += __shfl_xor(kv, 4, 64);
        float sc = fminf(fmaxf(kv * INV_SCALE, -10.f), 10.f);
        float e  = expf(sc);
        float mn = fmaxf(m, e);
        float r  = expf(m - mn);
        float w  = expf(e - mn);
        S = S * r + w;
        u = u * r + w * v;
        m = mn;
    }
    U[d * DM + t] = (S > 0.f) ? u / S : 0.f;
}

__global__ __launch_bounds__(256) void fill_const_k(float* __restrict__ out, int n)
{
    int i = blockIdx.x * 256 + threadIdx.x;
    if (i < n) out[i] = 100.0f;
}

// ---------------------------------------------------------------------------
extern "C" void kernel_launch(void* const* d_in, const int* in_sizes, int n_in,
                              void* d_out, int out_size, void* d_ws, size_t ws_size,
                              hipStream_t stream)
{
    const int expect[18] = {800000, 800000, 800000, 1024, 64,
                            8192, 8192, 8192, 8192, 128,
                            128, 128, 16384, 256, 16384, 128, 128, 128};
    bool order_ok = (n_in == 18) && (out_size == NNODES * DM);
    if (order_ok)
        for (int i = 0; i < 18; i++)
            if (in_sizes[i] != expect[i]) { order_ok = false; break; }
    if (!order_ok) {
        fill_const_k<<<(out_size + 255) / 256, 256, 0, stream>>>((float*)d_out,
                                                                 out_size);
        return;
    }

    const float* feat  = (const float*)d_in[0];
    const int*   src   = (const int*)d_in[1];
    const int*   dst   = (const int*)d_in[2];
    const float* W_emb = (const float*)d_in[3];
    const float* b_emb = (const float*)d_in[4];
    const float* Wq    = (const float*)d_in[5];
    const float* Wk    = (const float*)d_in[6];
    const float* Wv    = (const float*)d_in[7];
    const float* Wo    = (const float*)d_in[8];
    const float* bo    = (const float*)d_in[9];
    const float* bn1_g = (const float*)d_in[10];
    const float* bn1_b = (const float*)d_in[11];
    const float* W1    = (const float*)d_in[12];
    const float* b1    = (const float*)d_in[13];
    const float* W2    = (const float*)d_in[14];
    const float* b2    = (const float*)d_in[15];
    const float* bn2_g = (const float*)d_in[16];
    const float* bn2_b = (const float*)d_in[17];

    const size_t ND = (size_t)NNODES * DM;
    float* ws     = (float*)d_ws;
    float* Hb     = ws;
    float* Qb     = Hb + ND;
    float* Kb     = Qb + ND;
    float* Vb     = Kb + ND;
    float* Ub     = Vb + ND;
    float* stats  = Ub + ND;
    int*   rowptr = (int*)(stats + 256);            // N+1
    int*   cursor = rowptr + (NNODES + 1);          // N
    int*   bsum   = cursor + NNODES;                // 200
    int*   nbr    = bsum + SCAN_BLOCKS;             // E
    float* Fb     = Qb;   // FFN hidden [N,128] aliases Qb+Kb (dead after attn)

    const size_t REQUIRED = (5 * ND + 256 + (NNODES + 1) + NNODES + SCAN_BLOCKS
                             + NEDGES) * 4;
    if (ws_size < REQUIRED) return;

    const int g64 = (NNODES + 63) / 64;   // 782
    const int g32 = (NNODES + 31) / 32;   // 1563
    const int gND = (int)(ND / 256);      // 12500
    const int gE  = (NEDGES + 255) / 256; // 3125

    // CSR by dst: count -> hierarchical scan (A/B/C) -> fill
    zero_int_k<<<(NNODES + 255) / 256, 256, 0, stream>>>(cursor, NNODES);
    count_k<<<gE, 256, 0, stream>>>(dst, cursor);
    csr_scanA<<<SCAN_BLOCKS, 256, 0, stream>>>(cursor, bsum);
    csr_scanB<<<1, 256, 0, stream>>>(bsum);
    csr_scanC<<<SCAN_BLOCKS, 256, 0, stream>>>(cursor, rowptr, bsum);
    fill_k<<<gE, 256, 0, stream>>>(src, dst, cursor, nbr);

    // embedding: H = feat @ W_emb + b_emb
    gemm_k<16, 64, 4, false, false, false>
        <<<g64, 256, 0, stream>>>(feat, W_emb, 0, b_emb, 0, Hb, nullptr, NNODES);

    for (int l = 0; l < 2; l++) {
        const int woff  = l * DM * DM;        // 4096
        const int w1off = l * DM * 2 * DM;    // 8192
        const int boff  = l * DM;             // 64
        const int b1off = l * 2 * DM;         // 128

        gemm_k<64, 64, 4, false, false, false>
            <<<g64, 256, 0, stream>>>(Hb, Wq, woff, nullptr, 0, Qb, nullptr, NNODES);
        gemm_k<64, 64, 4, false, false, false>
            <<<g64, 256, 0, stream>>>(Hb, Wk, woff, nullptr, 0, Kb, nullptr, NNODES);
        gemm_k<64, 64, 4, false, false, false>
            <<<g64, 256, 0, stream>>>(Hb, Wv, woff, nullptr, 0, Vb, nullptr, NNODES);

        attn_k<<<NNODES, 64, 0, stream>>>(Qb, Kb, Vb, rowptr, nbr, Ub);

        // h = h_in1 + U @ Wo + bo ; fused BN stats ; BN apply
        hipMemsetAsync(stats, 0, 128 * 4, stream);
        gemm_k<64, 64, 4, false, true, true>
            <<<g64, 256, 0, stream>>>(Ub, Wo, woff, bo, boff, Hb, stats, NNODES);
        bn_fin<<<1, 64, 0, stream>>>(stats);
        bn_apply<<<gND, 256, 0, stream>>>(Hb, Hb, stats, bn1_g, boff, bn1_b, boff);

        // FFN: F = relu(H @ W1 + b1) ; H = H + F @ W2 + b2 ; BN
        gemm_k<64, 128, 4, true, false, false>
            <<<g32, 256, 0, stream>>>(Hb, W1, w1off, b1, b1off, Fb, nullptr, NNODES);
        hipMemsetAsync(stats, 0, 128 * 4, stream);
        gemm_k<128, 64, 2, false, true, true>
            <<<g32, 256, 0, stream>>>(Fb, W2, w1off, b2, boff, Hb, stats, NNODES);
        bn_fin<<<1, 64, 0, stream>>>(stats);
        // last BN of last layer writes the final output directly
        float* outp = (l == 1) ? (float*)d_out : Hb;
        bn_apply<<<gND, 256, 0, stream>>>(Hb, outp, stats, bn2_g, boff, bn2_b, boff);
    }
}

// Round 15
// 728.198 us; speedup vs baseline: 2.6235x; 1.0016x over previous
//
#include <hip/hip_runtime.h>

#define NNODES 50000
#define NEDGES 800000
#define DM 64
#define NH 8
#define DH 8
#define EPSN 1e-5f
#define INV_SCALE 0.3535533905932738f   // 1/sqrt(8)
#define SCAN_BLOCKS 200                  // NNODES = 200 * 250 exactly
#define SCAN_CHUNK  250

// ---------------------------------------------------------------------------
// Tiled GEMM (r13: unroll-2 + launch_bounds(256,2), no spill; r15: float4
// staging).  C[N x KB] = act(A @ W[woff..] + bias[boff..]) (+ C residual)
// STATS: accumulates per-column sum/sumsq into stats[0..KB-1],[KB..2KB-1].
// ---------------------------------------------------------------------------
template<int KA, int KB, int R, bool RELU, bool RES, bool STATS>
__global__ __launch_bounds__(256, 2) void gemm_k(const float* __restrict__ A,
    const float* __restrict__ W, int woff,
    const float* __restrict__ bias, int boff,
    float* __restrict__ C, float* __restrict__ stats, int Nrows)
{
    constexpr int CG   = KB / 4;
    constexpr int RG   = 256 / CG;
    constexpr int ROWS = RG * R;
    constexpr int APAD = KA + 4;
    constexpr int KAq  = KA / 4;

    __shared__ __align__(16) float sW[KA * KB];
    __shared__ __align__(16) float sA[ROWS * APAD];

    const int tid  = threadIdx.x;
    const int row0 = blockIdx.x * ROWS;

    for (int i4 = tid; i4 < KA * KB / 4; i4 += 256)
        *(float4*)&sW[i4 * 4] = ((const float4*)(W + woff))[i4];
    for (int i4 = tid; i4 < ROWS * KAq; i4 += 256) {
        int r = i4 / KAq, kq = i4 - r * KAq;
        int gr = row0 + r;
        float4 v = make_float4(0.f, 0.f, 0.f, 0.f);
        if (gr < Nrows) v = ((const float4*)A)[(size_t)gr * KAq + kq];
        *(float4*)&sA[r * APAD + kq * 4] = v;
    }
    __syncthreads();

    const int cg = tid % CG, rg = tid / CG;
    const int c0 = cg * 4, r0 = rg * R;

    float4 acc[R];
#pragma unroll
    for (int rr = 0; rr < R; rr++) acc[rr] = make_float4(0.f, 0.f, 0.f, 0.f);

#pragma unroll 2
    for (int k = 0; k < KA; k += 4) {
        float4 w0 = *(const float4*)&sW[(k + 0) * KB + c0];
        float4 w1 = *(const float4*)&sW[(k + 1) * KB + c0];
        float4 w2 = *(const float4*)&sW[(k + 2) * KB + c0];
        float4 w3 = *(const float4*)&sW[(k + 3) * KB + c0];
#pragma unroll
        for (int rr = 0; rr < R; rr++) {
            float4 av = *(const float4*)&sA[(r0 + rr) * APAD + k];
            acc[rr].x += av.x * w0.x + av.y * w1.x + av.z * w2.x + av.w * w3.x;
            acc[rr].y += av.x * w0.y + av.y * w1.y + av.z * w2.y + av.w * w3.y;
            acc[rr].z += av.x * w0.z + av.y * w1.z + av.z * w2.z + av.w * w3.z;
            acc[rr].w += av.x * w0.w + av.y * w1.w + av.z * w2.w + av.w * w3.w;
        }
    }

    float4 bv = make_float4(0.f, 0.f, 0.f, 0.f);
    if (bias) {
        bv.x = bias[boff + c0];     bv.y = bias[boff + c0 + 1];
        bv.z = bias[boff + c0 + 2]; bv.w = bias[boff + c0 + 3];
    }

    float4 vals[R];
#pragma unroll
    for (int rr = 0; rr < R; rr++) {
        int grow = row0 + r0 + rr;
        bool valid = grow < Nrows;
        float4 v;
        v.x = acc[rr].x + bv.x; v.y = acc[rr].y + bv.y;
        v.z = acc[rr].z + bv.z; v.w = acc[rr].w + bv.w;
        if (RELU) {
            v.x = fmaxf(v.x, 0.f); v.y = fmaxf(v.y, 0.f);
            v.z = fmaxf(v.z, 0.f); v.w = fmaxf(v.w, 0.f);
        }
        if (valid) {
            if (RES) {
                float4 old = *(const float4*)&C[(size_t)grow * KB + c0];
                v.x += old.x; v.y += old.y; v.z += old.z; v.w += old.w;
            }
            *(float4*)&C[(size_t)grow * KB + c0] = v;
        } else {
            v = make_float4(0.f, 0.f, 0.f, 0.f);
        }
        vals[rr] = v;
    }

    if (STATS) {
        __syncthreads();
        float4 cs = make_float4(0.f, 0.f, 0.f, 0.f);
#pragma unroll
        for (int rr = 0; rr < R; rr++) {
            cs.x += vals[rr].x; cs.y += vals[rr].y;
            cs.z += vals[rr].z; cs.w += vals[rr].w;
        }
        *(float4*)&sA[rg * KB + c0] = cs;
        __syncthreads();
        if (tid < KB) {
            float s = 0.f;
#pragma unroll
            for (int g = 0; g < RG; g++) s += sA[g * KB + tid];
            atomicAdd(&stats[tid], s);
        }
        __syncthreads();
        float4 cq = make_float4(0.f, 0.f, 0.f, 0.f);
#pragma unroll
        for (int rr = 0; rr < R; rr++) {
            cq.x += vals[rr].x * vals[rr].x; cq.y += vals[rr].y * vals[rr].y;
            cq.z += vals[rr].z * vals[rr].z; cq.w += vals[rr].w * vals[rr].w;
        }
        *(float4*)&sA[rg * KB + c0] = cq;
        __syncthreads();
        if (tid < KB) {
            float s = 0.f;
#pragma unroll
            for (int g = 0; g < RG; g++) s += sA[g * KB + tid];
            atomicAdd(&stats[KB + tid], s);
        }
    }
}

// ---------------------------------------------------------------------------
// Fused QKV: stage H tile once, loop Wq/Wk/Wv through one sW buffer.
// Saves 2x H reads and 2 launches vs three gemm_k calls.
// ---------------------------------------------------------------------------
__global__ __launch_bounds__(256, 2) void qkv_k(const float* __restrict__ A,
    const float* __restrict__ Wq, const float* __restrict__ Wk,
    const float* __restrict__ Wv, int woff,
    float* __restrict__ Qo, float* __restrict__ Ko, float* __restrict__ Vo,
    int Nrows)
{
    constexpr int APAD = 68;
    __shared__ __align__(16) float sW[64 * 64];
    __shared__ __align__(16) float sA[64 * APAD];

    const int tid  = threadIdx.x;
    const int row0 = blockIdx.x * 64;

    for (int i4 = tid; i4 < 64 * 16; i4 += 256) {   // 64 rows x 16 f4
        int r = i4 >> 4, kq = i4 & 15;
        int gr = row0 + r;
        float4 v = make_float4(0.f, 0.f, 0.f, 0.f);
        if (gr < Nrows) v = ((const float4*)A)[(size_t)gr * 16 + kq];
        *(float4*)&sA[r * APAD + kq * 4] = v;
    }

    const float* Ws[3]   = {Wq, Wk, Wv};
    float*       Outs[3] = {Qo, Ko, Vo};

    const int cg = tid & 15, rg = tid >> 4;
    const int c0 = cg * 4, r0 = rg * 4;

    for (int m = 0; m < 3; m++) {
        __syncthreads();   // protects sW (WAR) and, first pass, sA stage
        for (int i4 = tid; i4 < 1024; i4 += 256)
            *(float4*)&sW[i4 * 4] = ((const float4*)(Ws[m] + woff))[i4];
        __syncthreads();

        float4 acc[4];
#pragma unroll
        for (int rr = 0; rr < 4; rr++) acc[rr] = make_float4(0.f, 0.f, 0.f, 0.f);

#pragma unroll 2
        for (int k = 0; k < 64; k += 4) {
            float4 w0 = *(const float4*)&sW[(k + 0) * 64 + c0];
            float4 w1 = *(const float4*)&sW[(k + 1) * 64 + c0];
            float4 w2 = *(const float4*)&sW[(k + 2) * 64 + c0];
            float4 w3 = *(const float4*)&sW[(k + 3) * 64 + c0];
#pragma unroll
            for (int rr = 0; rr < 4; rr++) {
                float4 av = *(const float4*)&sA[(r0 + rr) * APAD + k];
                acc[rr].x += av.x * w0.x + av.y * w1.x + av.z * w2.x + av.w * w3.x;
                acc[rr].y += av.x * w0.y + av.y * w1.y + av.z * w2.y + av.w * w3.y;
                acc[rr].z += av.x * w0.z + av.y * w1.z + av.z * w2.z + av.w * w3.z;
                acc[rr].w += av.x * w0.w + av.y * w1.w + av.z * w2.w + av.w * w3.w;
            }
        }

#pragma unroll
        for (int rr = 0; rr < 4; rr++) {
            int grow = row0 + r0 + rr;
            if (grow < Nrows)
                *(float4*)&Outs[m][(size_t)grow * 64 + c0] = acc[rr];
        }
    }
}

// bn_apply derives mu/istd from raw sums (bn_fin folded in; 4 launches saved)
__global__ __launch_bounds__(256) void bn_apply(const float* __restrict__ Hin,
    float* __restrict__ Hout, const float* __restrict__ stats,
    const float* __restrict__ g, int goff, const float* __restrict__ b, int boff)
{
    int i = blockIdx.x * 256 + threadIdx.x;
    if (i >= NNODES * DM) return;
    int c = i & 63;
    float mu  = stats[c] * (1.0f / NNODES);
    float var = stats[64 + c] * (1.0f / NNODES) - mu * mu;   // biased (jnp.var)
    float istd = rsqrtf(fmaxf(var, 0.0f) + EPSN);
    Hout[i] = (Hin[i] - mu) * istd * g[goff + c] + b[boff + c];
}

// ---------------------------------------------------------------------------
// CSR by dst: count -> hierarchical 3-phase scan -> fill (stores src + eid).
// ---------------------------------------------------------------------------
__global__ __launch_bounds__(256) void zero_int_k(int* __restrict__ p, int n)
{
    int i = blockIdx.x * 256 + threadIdx.x;
    if (i < n) p[i] = 0;
}

__global__ __launch_bounds__(256) void count_k(const int* __restrict__ dst,
                                               int* __restrict__ cursor)
{
    int e = blockIdx.x * 256 + threadIdx.x;
    if (e < NEDGES) atomicAdd(&cursor[dst[e]], 1);
}

__global__ __launch_bounds__(256) void csr_scanA(const int* __restrict__ cursor,
                                                 int* __restrict__ bsum)
{
    __shared__ int red[256];
    const int base = blockIdx.x * SCAN_CHUNK;
    int s = 0;
    for (int i = threadIdx.x; i < SCAN_CHUNK; i += 256) s += cursor[base + i];
    red[threadIdx.x] = s;
    __syncthreads();
    for (int o = 128; o > 0; o >>= 1) {
        if (threadIdx.x < o) red[threadIdx.x] += red[threadIdx.x + o];
        __syncthreads();
    }
    if (threadIdx.x == 0) bsum[blockIdx.x] = red[0];
}

__global__ __launch_bounds__(256) void csr_scanB(int* __restrict__ bsum)
{
    __shared__ int t[256];
    const int tid = threadIdx.x;
    int v = (tid < SCAN_BLOCKS) ? bsum[tid] : 0;
    t[tid] = v;
    __syncthreads();
    for (int off = 1; off < 256; off <<= 1) {
        int x = (tid >= off) ? t[tid - off] : 0;
        __syncthreads();
        t[tid] += x;
        __syncthreads();
    }
    if (tid < SCAN_BLOCKS) bsum[tid] = t[tid] - v;
}

__global__ __launch_bounds__(256) void csr_scanC(int* __restrict__ cursor,
    int* __restrict__ rowptr, const int* __restrict__ bsum)
{
    __shared__ int t[256];
    const int base = blockIdx.x * SCAN_CHUNK;
    const int tid  = threadIdx.x;
    int deg = (tid < SCAN_CHUNK) ? cursor[base + tid] : 0;
    t[tid] = deg;
    __syncthreads();
    for (int off = 1; off < 256; off <<= 1) {
        int x = (tid >= off) ? t[tid - off] : 0;
        __syncthreads();
        t[tid] += x;
        __syncthreads();
    }
    int excl = bsum[blockIdx.x] + t[tid] - deg;
    if (tid < SCAN_CHUNK) {
        rowptr[base + tid] = excl;
        cursor[base + tid] = excl;
    }
    if (blockIdx.x == 0 && tid == 0) rowptr[NNODES] = NEDGES;
}

__global__ __launch_bounds__(256) void fill_k(const int* __restrict__ src,
    const int* __restrict__ dst, int* __restrict__ cursor,
    int* __restrict__ nbr, int* __restrict__ eids)
{
    int e = blockIdx.x * 256 + threadIdx.x;
    if (e >= NEDGES) return;
    int pos = atomicAdd(&cursor[dst[e]], 1);
    nbr[pos] = src[e];
    if (eids) eids[pos] = e;
}

// ---------------------------------------------------------------------------
// Two-phase attention (r15):
// score_k: one thread per (edge, head): EW[e*8+h] = exp(clip(K[s]h.Q[d]h/sqrt8))
// agg_k:   wave per dst: online max/rescale over precomputed scores (no K
//          gathers, no shuffles, no redundant per-lane exp of the score).
// ---------------------------------------------------------------------------
__global__ __launch_bounds__(256) void score_k(const float* __restrict__ Q,
    const float* __restrict__ K, const int* __restrict__ src,
    const int* __restrict__ dst, float* __restrict__ EW)
{
    int t = blockIdx.x * 256 + threadIdx.x;
    if (t >= NEDGES * NH) return;
    int e = t >> 3, h = t & 7;
    int s = src[e], d = dst[e];
    const float4* kp = (const float4*)(K + s * DM + h * DH);
    const float4* qp = (const float4*)(Q + d * DM + h * DH);
    float4 k0 = kp[0], k1 = kp[1], q0 = qp[0], q1 = qp[1];
    float dot = k0.x * q0.x + k0.y * q0.y + k0.z * q0.z + k0.w * q0.w
              + k1.x * q1.x + k1.y * q1.y + k1.z * q1.z + k1.w * q1.w;
    float sc = fminf(fmaxf(dot * INV_SCALE, -10.f), 10.f);
    EW[t] = expf(sc);
}

__global__ __launch_bounds__(64) void agg_k(const float* __restrict__ V,
    const float* __restrict__ EW, const int* __restrict__ rowptr,
    const int* __restrict__ nbr, const int* __restrict__ eids,
    float* __restrict__ U)
{
    const int d = blockIdx.x;
    const int t = threadIdx.x;           // t = h*8 + j
    const int h = t >> 3;
    const int e0 = rowptr[d], e1 = rowptr[d + 1];

    float m = 0.0f, S = 0.0f, u = 0.0f;
    for (int p = e0; p < e1; p++) {
        int s   = nbr[p];
        int eid = eids[p];
        float ev = EW[eid * NH + h];
        float v  = V[s * DM + t];
        float mn = fmaxf(m, ev);
        float r  = expf(m - mn);
        float w  = expf(ev - mn);
        S = S * r + w;
        u = u * r + w * v;
        m = mn;
    }
    U[d * DM + t] = (S > 0.f) ? u / S : 0.f;
}

// Fallback single-pass attention (r14-proven) when ws too small for EW.
__global__ __launch_bounds__(64) void attn_k(const float* __restrict__ Q,
    const float* __restrict__ K, const float* __restrict__ V,
    const int* __restrict__ rowptr, const int* __restrict__ nbr,
    float* __restrict__ U)
{
    const int d = blockIdx.x;
    const int t = threadIdx.x;
    const int e0 = rowptr[d], e1 = rowptr[d + 1];
    const float q = Q[d * DM + t];

    float m = 0.0f, S = 0.0f, u = 0.0f;
    for (int p = e0; p < e1; p++) {
        int s = nbr[p];
        float kv = K[s * DM + t] * q;
        float v  = V[s * DM + t];
        kv += __shfl_xor(kv, 1, 64);
        kv += __shfl_xor(kv, 2, 64);
        kv += __shfl_xor(kv, 4, 64);
        float sc = fminf(fmaxf(kv * INV_SCALE, -10.f), 10.f);
        float e  = expf(sc);
        float mn = fmaxf(m, e);
        float r  = expf(m - mn);
        float w  = expf(e - mn);
        S = S * r + w;
        u = u * r + w * v;
        m = mn;
    }
    U[d * DM + t] = (S > 0.f) ? u / S : 0.f;
}

__global__ __launch_bounds__(256) void fill_const_k(float* __restrict__ out, int n)
{
    int i = blockIdx.x * 256 + threadIdx.x;
    if (i < n) out[i] = 100.0f;
}

// ---------------------------------------------------------------------------
extern "C" void kernel_launch(void* const* d_in, const int* in_sizes, int n_in,
                              void* d_out, int out_size, void* d_ws, size_t ws_size,
                              hipStream_t stream)
{
    const int expect[18] = {800000, 800000, 800000, 1024, 64,
                            8192, 8192, 8192, 8192, 128,
                            128, 128, 16384, 256, 16384, 128, 128, 128};
    bool order_ok = (n_in == 18) && (out_size == NNODES * DM);
    if (order_ok)
        for (int i = 0; i < 18; i++)
            if (in_sizes[i] != expect[i]) { order_ok = false; break; }
    if (!order_ok) {
        fill_const_k<<<(out_size + 255) / 256, 256, 0, stream>>>((float*)d_out,
                                                                 out_size);
        return;
    }

    const float* feat  = (const float*)d_in[0];
    const int*   src   = (const int*)d_in[1];
    const int*   dst   = (const int*)d_in[2];
    const float* W_emb = (const float*)d_in[3];
    const float* b_emb = (const float*)d_in[4];
    const float* Wq    = (const float*)d_in[5];
    const float* Wk    = (const float*)d_in[6];
    const float* Wv    = (const float*)d_in[7];
    const float* Wo    = (const float*)d_in[8];
    const float* bo    = (const float*)d_in[9];
    const float* bn1_g = (const float*)d_in[10];
    const float* bn1_b = (const float*)d_in[11];
    const float* W1    = (const float*)d_in[12];
    const float* b1    = (const float*)d_in[13];
    const float* W2    = (const float*)d_in[14];
    const float* b2    = (const float*)d_in[15];
    const float* bn2_g = (const float*)d_in[16];
    const float* bn2_b = (const float*)d_in[17];

    const size_t ND = (size_t)NNODES * DM;
    float* ws     = (float*)d_ws;
    float* Hb     = ws;
    float* Qb     = Hb + ND;
    float* Kb     = Qb + ND;
    float* Vb     = Kb + ND;
    float* Ub     = Vb + ND;
    float* stats  = Ub + ND;
    int*   rowptr = (int*)(stats + 256);            // N+1
    int*   cursor = rowptr + (NNODES + 1);          // N
    int*   bsum   = cursor + NNODES;                // 200
    int*   nbr    = bsum + SCAN_BLOCKS;             // E
    int*   eids   = nbr + NEDGES;                   // E      (two-phase only)
    float* EW     = (float*)(eids + NEDGES);        // E * 8  (two-phase only)
    float* Fb     = Qb;   // FFN hidden [N,128] aliases Qb+Kb (dead after attn)

    const size_t BASE = (5 * ND + 256) * 4
                      + ((NNODES + 1) + NNODES + SCAN_BLOCKS + NEDGES) * 4;
    const size_t BIG  = BASE + (size_t)NEDGES * 4 + (size_t)NEDGES * NH * 4;
    if (ws_size < BASE) return;
    const bool twophase = (ws_size >= BIG);

    const int g64 = (NNODES + 63) / 64;   // 782
    const int g32 = (NNODES + 31) / 32;   // 1563
    const int gND = (int)(ND / 256);      // 12500
    const int gE  = (NEDGES + 255) / 256; // 3125
    const int gEH = (NEDGES * NH) / 256;  // 25000

    // CSR by dst
    zero_int_k<<<(NNODES + 255) / 256, 256, 0, stream>>>(cursor, NNODES);
    count_k<<<gE, 256, 0, stream>>>(dst, cursor);
    csr_scanA<<<SCAN_BLOCKS, 256, 0, stream>>>(cursor, bsum);
    csr_scanB<<<1, 256, 0, stream>>>(bsum);
    csr_scanC<<<SCAN_BLOCKS, 256, 0, stream>>>(cursor, rowptr, bsum);
    fill_k<<<gE, 256, 0, stream>>>(src, dst, cursor, nbr,
                                   twophase ? eids : nullptr);

    // embedding: H = feat @ W_emb + b_emb
    gemm_k<16, 64, 4, false, false, false>
        <<<g64, 256, 0, stream>>>(feat, W_emb, 0, b_emb, 0, Hb, nullptr, NNODES);

    for (int l = 0; l < 2; l++) {
        const int woff  = l * DM * DM;        // 4096
        const int w1off = l * DM * 2 * DM;    // 8192
        const int boff  = l * DM;             // 64
        const int b1off = l * 2 * DM;         // 128

        qkv_k<<<g64, 256, 0, stream>>>(Hb, Wq, Wk, Wv, woff, Qb, Kb, Vb, NNODES);

        if (twophase) {
            score_k<<<gEH, 256, 0, stream>>>(Qb, Kb, src, dst, EW);
            agg_k<<<NNODES, 64, 0, stream>>>(Vb, EW, rowptr, nbr, eids, Ub);
        } else {
            attn_k<<<NNODES, 64, 0, stream>>>(Qb, Kb, Vb, rowptr, nbr, Ub);
        }

        // h = h_in1 + U @ Wo + bo ; fused BN stats ; BN apply (fin folded in)
        hipMemsetAsync(stats, 0, 128 * 4, stream);
        gemm_k<64, 64, 4, false, true, true>
            <<<g64, 256, 0, stream>>>(Ub, Wo, woff, bo, boff, Hb, stats, NNODES);
        bn_apply<<<gND, 256, 0, stream>>>(Hb, Hb, stats, bn1_g, boff, bn1_b, boff);

        // FFN: F = relu(H @ W1 + b1) ; H = H + F @ W2 + b2 ; BN
        gemm_k<64, 128, 4, true, false, false>
            <<<g32, 256, 0, stream>>>(Hb, W1, w1off, b1, b1off, Fb, nullptr, NNODES);
        hipMemsetAsync(stats, 0, 128 * 4, stream);
        gemm_k<128, 64, 2, false, true, true>
            <<<g32, 256, 0, stream>>>(Fb, W2, w1off, b2, boff, Hb, stats, NNODES);
        // last BN of last layer writes the final output directly
        float* outp = (l == 1) ? (float*)d_out : Hb;
        bn_apply<<<gND, 256, 0, stream>>>(Hb, outp, stats, bn2_g, boff, bn2_b, boff);
    }
}